// Round 1
// baseline (793.966 us; speedup 1.0000x reference)
//
#include <hip/hip_runtime.h>
#include <cstdint>

#define B_   4
#define C_   128
#define H_   128
#define W_   128
#define HP_  130
#define WP_  130
#define O_   256
#define HW_  (H_*W_)          // 16384
#define NPOS (B_*HW_)         // 65536

// ws layout (in floats)
#define XPAD_SZ   (B_*HP_*WP_*C_)        // 8,652,800
#define OFF_OFF   XPAD_SZ
#define OFF_SZ    (B_*HW_*18)            // 1,179,648
#define WREP_OFF  (OFF_OFF + OFF_SZ)
#define WREP_SZ   (9*C_*O_)              // 294,912
#define STATS_OFF (WREP_OFF + WREP_SZ)
#define STATS_SZ  1024

// ---------------- K1: NCHW -> padded NHWC transpose ----------------
__global__ void k_transpose(const float* __restrict__ x, float* __restrict__ xpad) {
    __shared__ float tile[32][33];
    int w0 = blockIdx.x * 32, c0 = blockIdx.y * 32;
    int bh = blockIdx.z;
    int b = bh >> 7, h = bh & 127;
    int tx = threadIdx.x, ty = threadIdx.y;
#pragma unroll
    for (int i = 0; i < 4; i++) {
        int c = c0 + ty + i * 8;
        tile[ty + i * 8][tx] = x[((b * C_ + c) * H_ + h) * W_ + w0 + tx];
    }
    __syncthreads();
#pragma unroll
    for (int i = 0; i < 4; i++) {
        int w = w0 + ty + i * 8;
        xpad[((b * HP_ + h + 1) * WP_ + (w + 1)) * C_ + c0 + tx] = tile[tx][ty + i * 8];
    }
}

// ---------------- K2: offset conv (18 out channels) ----------------
__global__ __launch_bounds__(256) void k_offconv(const float* __restrict__ xpad,
                                                 const float* __restrict__ p_w,
                                                 const float* __restrict__ p_b,
                                                 float* __restrict__ off) {
    __shared__ float wl[C_ * 20];   // one tap's weights, j padded 18->20
    int t = threadIdx.x;
    int b = blockIdx.y;
    int p = blockIdx.x * 256 + t;
    int h = p >> 7, w = p & 127;
    float acc[20];
#pragma unroll
    for (int j = 0; j < 20; j++) acc[j] = 0.f;
    const float* xb = xpad + b * HP_ * WP_ * C_;

    for (int tap = 0; tap < 9; tap++) {
        __syncthreads();
        for (int i = t; i < C_ * 20; i += 256) {
            int c = i / 20, j = i % 20;
            wl[i] = (j < 18) ? p_w[(j * C_ + c) * 9 + tap] : 0.f;
        }
        __syncthreads();
        int kh = tap / 3, kw = tap % 3;
        const float* src = xb + ((h + kh) * WP_ + (w + kw)) * C_;
        for (int c4 = 0; c4 < C_; c4 += 4) {
            float4 v = *(const float4*)(src + c4);
#pragma unroll
            for (int cc = 0; cc < 4; cc++) {
                float vv = (&v.x)[cc];
                const float* wrow = &wl[(c4 + cc) * 20];
#pragma unroll
                for (int j4 = 0; j4 < 5; j4++) {
                    float4 wj = *(const float4*)(wrow + j4 * 4);
                    acc[j4 * 4 + 0] += wj.x * vv;
                    acc[j4 * 4 + 1] += wj.y * vv;
                    acc[j4 * 4 + 2] += wj.z * vv;
                    acc[j4 * 4 + 3] += wj.w * vv;
                }
            }
        }
    }
#pragma unroll
    for (int j = 0; j < 18; j++)
        off[(size_t)(b * HW_ + p) * 18 + j] = acc[j] + p_b[j];
}

// ---------------- K2b: repack w_conv (o,c,3,3) -> wrep[n][c][o] ----------------
__global__ void k_repack(const float* __restrict__ w_conv, float* __restrict__ wrep) {
    int i = blockIdx.x * 256 + threadIdx.x;
    if (i < WREP_SZ) {
        int o = i & 255;
        int c = (i >> 8) & 127;
        int n = i >> 15;
        wrep[i] = w_conv[(o * C_ + c) * 9 + n];
    }
}

// ---------------- K3: fused gather + GEMM + BN partial sums ----------------
__global__ __launch_bounds__(256, 2) void k_main(const float* __restrict__ xpad,
                                                 const float* __restrict__ off,
                                                 const float* __restrict__ wrep,
                                                 float* __restrict__ out,
                                                 float* __restrict__ stats) {
    __shared__ float wl[32 * 128];   // W chunk: [k=32][o=128]
    __shared__ float vl[32 * 128];   // V chunk: [k=32][pos=128]
    __shared__ int   pbase[4][128];
    __shared__ float pg[4][128];
    __shared__ float red[2][128];

    int t = threadIdx.x;
    int h  = blockIdx.x;           // row
    int o0 = blockIdx.y * 128;     // 0 or 128
    int b  = blockIdx.z;
    const float* xb = xpad + b * HP_ * WP_ * C_;
    int to = t & 15, tp = t >> 4;

    float acc[8][8];
#pragma unroll
    for (int i = 0; i < 8; i++)
#pragma unroll
        for (int j = 0; j < 8; j++) acc[i][j] = 0.f;

    for (int n = 0; n < 9; n++) {
        if (t < 128) {
            int w = t;
            float offx = off[(size_t)(b * HW_ + h * W_ + w) * 18 + n];
            float offy = off[(size_t)(b * HW_ + h * W_ + w) * 18 + 9 + n];
            int dxn = n / 3 - 1, dyn = n % 3 - 1;
            float px = (float)(h + 1 + dxn) + offx;
            float py = (float)(w + 1 + dyn) + offy;
            float pcx = fminf(fmaxf(px, 0.f), 129.f);
            float pcy = fminf(fmaxf(py, 0.f), 129.f);
            float fx = floorf(px), fy = floorf(py);
            float q0x = fminf(fmaxf(fx, 0.f), 129.f);
            float q0y = fminf(fmaxf(fy, 0.f), 129.f);
            float q1x = fminf(fmaxf(fx + 1.f, 0.f), 129.f);
            float q1y = fminf(fmaxf(fy + 1.f, 0.f), 129.f);
            float wx0 = 1.f + (q0x - pcx), wx1 = 1.f - (q1x - pcx);
            float wy0 = 1.f + (q0y - pcy), wy1 = 1.f - (q1y - pcy);
            int i0x = (int)q0x, i0y = (int)q0y, i1x = (int)q1x, i1y = (int)q1y;
            pbase[0][w] = (i0x * WP_ + i0y) * C_;
            pbase[1][w] = (i1x * WP_ + i1y) * C_;
            pbase[2][w] = (i0x * WP_ + i1y) * C_;
            pbase[3][w] = (i1x * WP_ + i0y) * C_;
            pg[0][w] = wx0 * wy0;
            pg[1][w] = wx1 * wy1;
            pg[2][w] = wx0 * wy1;
            pg[3][w] = wx1 * wy0;
        }
        for (int ch = 0; ch < 4; ch++) {
            __syncthreads();
            // stage W chunk
#pragma unroll
            for (int r = 0; r < 4; r++) {
                int f = r * 256 + t;
                int k = f >> 5;
                int o4 = (f & 31) << 2;
                *(float4*)&wl[k * 128 + o4] =
                    *(const float4*)&wrep[(size_t)(n * C_ + ch * 32 + k) * O_ + o0 + o4];
            }
            // build V chunk (bilinear gather)
            {
                int pos = t & 127;
                int cg = t >> 7;
                int b0 = pbase[0][pos], b1 = pbase[1][pos], b2 = pbase[2][pos], b3 = pbase[3][pos];
                float g0 = pg[0][pos], g1 = pg[1][pos], g2 = pg[2][pos], g3 = pg[3][pos];
#pragma unroll
                for (int i4 = 0; i4 < 4; i4++) {
                    int cl = cg * 16 + i4 * 4;
                    int cglob = ch * 32 + cl;
                    float4 A  = *(const float4*)(xb + b0 + cglob);
                    float4 Bv = *(const float4*)(xb + b1 + cglob);
                    float4 Cv = *(const float4*)(xb + b2 + cglob);
                    float4 Dv = *(const float4*)(xb + b3 + cglob);
                    vl[(cl + 0) * 128 + pos] = g0 * A.x + g1 * Bv.x + g2 * Cv.x + g3 * Dv.x;
                    vl[(cl + 1) * 128 + pos] = g0 * A.y + g1 * Bv.y + g2 * Cv.y + g3 * Dv.y;
                    vl[(cl + 2) * 128 + pos] = g0 * A.z + g1 * Bv.z + g2 * Cv.z + g3 * Dv.z;
                    vl[(cl + 3) * 128 + pos] = g0 * A.w + g1 * Bv.w + g2 * Cv.w + g3 * Dv.w;
                }
            }
            __syncthreads();
            // GEMM on the chunk
#pragma unroll 4
            for (int k = 0; k < 32; k++) {
                float4 a0 = *(const float4*)&wl[k * 128 + to * 8];
                float4 a1 = *(const float4*)&wl[k * 128 + to * 8 + 4];
                float4 v0 = *(const float4*)&vl[k * 128 + tp * 8];
                float4 v1 = *(const float4*)&vl[k * 128 + tp * 8 + 4];
                float av[8] = {a0.x, a0.y, a0.z, a0.w, a1.x, a1.y, a1.z, a1.w};
                float bv[8] = {v0.x, v0.y, v0.z, v0.w, v1.x, v1.y, v1.z, v1.w};
#pragma unroll
                for (int i = 0; i < 8; i++)
#pragma unroll
                    for (int j = 0; j < 8; j++)
                        acc[i][j] += av[i] * bv[j];
            }
        }
    }

    // epilogue: write out + BN partial sums
    __syncthreads();
    if (t < 128) { red[0][t] = 0.f; red[1][t] = 0.f; }
    __syncthreads();
    float* outb = out + ((size_t)(b * O_ + o0)) * HW_ + h * W_;
#pragma unroll
    for (int i = 0; i < 8; i++) {
        int ol = to * 8 + i;
        float s = 0.f, s2 = 0.f;
#pragma unroll
        for (int j = 0; j < 8; j++) { float v = acc[i][j]; s += v; s2 += v * v; }
        atomicAdd(&red[0][ol], s);
        atomicAdd(&red[1][ol], s2);
        *(float4*)(outb + (size_t)ol * HW_ + tp * 8) =
            make_float4(acc[i][0], acc[i][1], acc[i][2], acc[i][3]);
        *(float4*)(outb + (size_t)ol * HW_ + tp * 8 + 4) =
            make_float4(acc[i][4], acc[i][5], acc[i][6], acc[i][7]);
    }
    __syncthreads();
    if (t < 128) {
        atomicAdd(&stats[o0 + t], red[0][t]);
        atomicAdd(&stats[256 + o0 + t], red[1][t]);
    }
}

// ---------------- K4: BN stats finalize ----------------
__global__ void k_bnstats(float* __restrict__ stats,
                          const float* __restrict__ gamma,
                          const float* __restrict__ beta) {
    int t = threadIdx.x;  // 256
    float s = stats[t], s2 = stats[256 + t];
    float mean = s * (1.f / 65536.f);
    float var = s2 * (1.f / 65536.f) - mean * mean;
    float sc = gamma[t] * rsqrtf(var + 1e-5f);
    float sh = beta[t] - mean * sc;
    stats[512 + t] = sc;
    stats[768 + t] = sh;
}

// ---------------- K5: normalize + leaky ReLU (in-place on d_out) ----------------
__global__ __launch_bounds__(256) void k_apply(float* __restrict__ out,
                                               const float* __restrict__ stats) {
    int idx = blockIdx.x * 256 + threadIdx.x;  // float4 index, 4,194,304 total
    int e = idx * 4;
    int o = (e >> 14) & 255;
    float sc = stats[512 + o], sh = stats[768 + o];
    float4 v = *(float4*)(out + e);
    v.x = v.x * sc + sh; v.x = (v.x >= 0.f) ? v.x : 0.1f * v.x;
    v.y = v.y * sc + sh; v.y = (v.y >= 0.f) ? v.y : 0.1f * v.y;
    v.z = v.z * sc + sh; v.z = (v.z >= 0.f) ? v.z : 0.1f * v.z;
    v.w = v.w * sc + sh; v.w = (v.w >= 0.f) ? v.w : 0.1f * v.w;
    *(float4*)(out + e) = v;
}

extern "C" void kernel_launch(void* const* d_in, const int* in_sizes, int n_in,
                              void* d_out, int out_size, void* d_ws, size_t ws_size,
                              hipStream_t stream) {
    const float* x      = (const float*)d_in[0];
    const float* p_w    = (const float*)d_in[1];
    const float* p_b    = (const float*)d_in[2];
    const float* w_conv = (const float*)d_in[3];
    const float* gamma  = (const float*)d_in[4];
    const float* beta   = (const float*)d_in[5];
    float* out = (float*)d_out;

    float* ws    = (float*)d_ws;
    float* xpad  = ws;
    float* off   = ws + OFF_OFF;
    float* wrep  = ws + WREP_OFF;
    float* stats = ws + STATS_OFF;

    hipMemsetAsync(xpad, 0, (size_t)XPAD_SZ * 4, stream);
    hipMemsetAsync(stats, 0, (size_t)STATS_SZ * 4, stream);

    k_transpose<<<dim3(W_ / 32, C_ / 32, B_ * H_), dim3(32, 8), 0, stream>>>(x, xpad);
    k_offconv<<<dim3(HW_ / 256, B_), 256, 0, stream>>>(xpad, p_w, p_b, off);
    k_repack<<<dim3((WREP_SZ + 255) / 256), 256, 0, stream>>>(w_conv, wrep);
    k_main<<<dim3(H_, 2, B_), 256, 0, stream>>>(xpad, off, wrep, out, stats);
    k_bnstats<<<1, 256, 0, stream>>>(stats, gamma, beta);
    k_apply<<<dim3(16384), 256, 0, stream>>>(out, stats);
}

// Round 2
// 605.510 us; speedup vs baseline: 1.3112x; 1.3112x over previous
//
#include <hip/hip_runtime.h>
#include <cstdint>

typedef __attribute__((ext_vector_type(8))) short bf16x8;
typedef __attribute__((ext_vector_type(4))) float f32x4;

#define B_   4
#define C_   128
#define H_   128
#define W_   128
#define HP_  130
#define WP_  130
#define O_   256
#define HW_  (H_*W_)          // 16384
#define NPOS (B_*HW_)         // 65536

// ws layout (in floats)
#define XPAD_SZ   (B_*HP_*WP_*C_)        // 8,652,800
#define OFF_OFF   XPAD_SZ
#define OFF_SZ    (B_*HW_*18)            // 1,179,648
#define WREPB_OFF (OFF_OFF + OFF_SZ)     // bf16 repacked weights: 294,912 ushorts = 147,456 floats
#define WREPB_SZF (9*C_*O_/2)
#define STATS_OFF (WREPB_OFF + WREPB_SZF)
#define STATS_SZ  1024

__device__ __forceinline__ unsigned pack_bf2(float a, float b) {
    // (bf16(b) << 16) | bf16(a), round-half-up (±1ulp vs RNE, irrelevant at bf16 scale)
    unsigned ua = __builtin_bit_cast(unsigned, a) + 0x8000u;
    unsigned ub = __builtin_bit_cast(unsigned, b) + 0x8000u;
    return __builtin_amdgcn_perm(ub, ua, 0x07060302u);
}

// ---------------- K1: NCHW -> padded NHWC transpose ----------------
__global__ void k_transpose(const float* __restrict__ x, float* __restrict__ xpad) {
    __shared__ float tile[32][33];
    int w0 = blockIdx.x * 32, c0 = blockIdx.y * 32;
    int bh = blockIdx.z;
    int b = bh >> 7, h = bh & 127;
    int tx = threadIdx.x, ty = threadIdx.y;
#pragma unroll
    for (int i = 0; i < 4; i++) {
        int c = c0 + ty + i * 8;
        tile[ty + i * 8][tx] = x[((b * C_ + c) * H_ + h) * W_ + w0 + tx];
    }
    __syncthreads();
#pragma unroll
    for (int i = 0; i < 4; i++) {
        int w = w0 + ty + i * 8;
        xpad[((b * HP_ + h + 1) * WP_ + (w + 1)) * C_ + c0 + tx] = tile[tx][ty + i * 8];
    }
}

// ---------------- K2: offset conv (18 out channels) ----------------
__global__ __launch_bounds__(256) void k_offconv(const float* __restrict__ xpad,
                                                 const float* __restrict__ p_w,
                                                 const float* __restrict__ p_b,
                                                 float* __restrict__ off) {
    __shared__ float wl[C_ * 20];   // one tap's weights, j padded 18->20
    int t = threadIdx.x;
    int b = blockIdx.y;
    int p = blockIdx.x * 256 + t;
    int h = p >> 7, w = p & 127;
    float acc[20];
#pragma unroll
    for (int j = 0; j < 20; j++) acc[j] = 0.f;
    const float* xb = xpad + b * HP_ * WP_ * C_;

    for (int tap = 0; tap < 9; tap++) {
        __syncthreads();
        for (int i = t; i < C_ * 20; i += 256) {
            int c = i / 20, j = i % 20;
            wl[i] = (j < 18) ? p_w[(j * C_ + c) * 9 + tap] : 0.f;
        }
        __syncthreads();
        int kh = tap / 3, kw = tap % 3;
        const float* src = xb + ((h + kh) * WP_ + (w + kw)) * C_;
        for (int c4 = 0; c4 < C_; c4 += 4) {
            float4 v = *(const float4*)(src + c4);
#pragma unroll
            for (int cc = 0; cc < 4; cc++) {
                float vv = (&v.x)[cc];
                const float* wrow = &wl[(c4 + cc) * 20];
#pragma unroll
                for (int j4 = 0; j4 < 5; j4++) {
                    float4 wj = *(const float4*)(wrow + j4 * 4);
                    acc[j4 * 4 + 0] += wj.x * vv;
                    acc[j4 * 4 + 1] += wj.y * vv;
                    acc[j4 * 4 + 2] += wj.z * vv;
                    acc[j4 * 4 + 3] += wj.w * vv;
                }
            }
        }
    }
#pragma unroll
    for (int j = 0; j < 18; j++)
        off[(size_t)(b * HW_ + p) * 18 + j] = acc[j] + p_b[j];
}

// ---------------- K2b: repack w_conv (o,c,3,3) -> bf16 fragment-major ----------------
// Layout: idx = ((((n*4+kc)*2+ob)*4 + kq)*128 + o_loc)*8 + ki8
//   o = ob*128 + o_loc,  c = kc*32 + kq*8 + ki8
__global__ void k_repack(const float* __restrict__ w_conv, unsigned short* __restrict__ wrepb) {
    int i = blockIdx.x * 256 + threadIdx.x;
    if (i < 9 * C_ * O_) {
        int ki8   = i & 7;
        int o_loc = (i >> 3) & 127;
        int kq    = (i >> 10) & 3;
        int ob    = (i >> 12) & 1;
        int kc    = (i >> 13) & 3;
        int n     = i >> 15;
        int o = ob * 128 + o_loc;
        int c = kc * 32 + kq * 8 + ki8;
        float f = w_conv[(o * C_ + c) * 9 + n];
        unsigned u = __builtin_bit_cast(unsigned, f);
        u += 0x7fffu + ((u >> 16) & 1u);   // RNE
        wrepb[i] = (unsigned short)(u >> 16);
    }
}

// ---------------- K3: fused gather + bf16 MFMA GEMM + BN partial sums ----------------
__global__ __launch_bounds__(256, 4) void k_main(const float* __restrict__ xpad,
                                                 const float* __restrict__ off,
                                                 const unsigned short* __restrict__ wrepb,
                                                 float* __restrict__ out,
                                                 float* __restrict__ stats) {
    // Fragment-major LDS: granule g = kq*128 + idx  ->  16B (8 bf16, k-inner)
    __shared__ short Al[4096];   // W tile: [kq][o(128)][8]   8 KB
    __shared__ short Vl[4096];   // V tile: [kq][pos(128)][8] 8 KB
    __shared__ int   pbase[4][128];
    __shared__ float pg[4][128];
    __shared__ float red[2][128];

    int t = threadIdx.x;
    int h  = blockIdx.x;
    int ob = blockIdx.y;
    int b  = blockIdx.z;
    int o0 = ob * 128;
    const float* xb = xpad + b * HP_ * WP_ * C_;

    int lane = t & 63, wv = t >> 6;
    int q = lane >> 4, l15 = lane & 15;
    int m0 = (wv & 1) * 64, n0 = (wv >> 1) * 64;
    int pos_g = t & 127, cg = t >> 7;

    f32x4 acc[4][4];
#pragma unroll
    for (int i = 0; i < 4; i++)
#pragma unroll
        for (int j = 0; j < 4; j++) acc[i][j] = (f32x4){0.f, 0.f, 0.f, 0.f};

    for (int n = 0; n < 9; n++) {
        if (t < 128) {
            int w = t;
            float offx = off[(size_t)(b * HW_ + h * W_ + w) * 18 + n];
            float offy = off[(size_t)(b * HW_ + h * W_ + w) * 18 + 9 + n];
            int dxn = n / 3 - 1, dyn = n % 3 - 1;
            float px = (float)(h + 1 + dxn) + offx;
            float py = (float)(w + 1 + dyn) + offy;
            float pcx = fminf(fmaxf(px, 0.f), 129.f);
            float pcy = fminf(fmaxf(py, 0.f), 129.f);
            float fx = floorf(px), fy = floorf(py);
            float q0x = fminf(fmaxf(fx, 0.f), 129.f);
            float q0y = fminf(fmaxf(fy, 0.f), 129.f);
            float q1x = fminf(fmaxf(fx + 1.f, 0.f), 129.f);
            float q1y = fminf(fmaxf(fy + 1.f, 0.f), 129.f);
            float wx0 = 1.f + (q0x - pcx), wx1 = 1.f - (q1x - pcx);
            float wy0 = 1.f + (q0y - pcy), wy1 = 1.f - (q1y - pcy);
            int i0x = (int)q0x, i0y = (int)q0y, i1x = (int)q1x, i1y = (int)q1y;
            pbase[0][w] = (i0x * WP_ + i0y) * C_;
            pbase[1][w] = (i1x * WP_ + i1y) * C_;
            pbase[2][w] = (i0x * WP_ + i1y) * C_;
            pbase[3][w] = (i1x * WP_ + i0y) * C_;
            pg[0][w] = wx0 * wy0;
            pg[1][w] = wx1 * wy1;
            pg[2][w] = wx0 * wy1;
            pg[3][w] = wx1 * wy0;
        }
        for (int kc = 0; kc < 4; kc++) {
            __syncthreads();
            // stage W chunk: 512 granules of 16B, fully contiguous
            {
                const uint4* wsrc = (const uint4*)(wrepb + ((size_t)((n * 4 + kc) * 2 + ob)) * 4096);
                uint4* ad = (uint4*)Al;
                ad[t]       = wsrc[t];
                ad[t + 256] = wsrc[t + 256];
            }
            // gather V chunk (bilinear, fp32 -> packed bf16)
            {
                int b0 = pbase[0][pos_g], b1 = pbase[1][pos_g], b2 = pbase[2][pos_g], b3 = pbase[3][pos_g];
                float g0 = pg[0][pos_g], g1 = pg[1][pos_g], g2 = pg[2][pos_g], g3 = pg[3][pos_g];
#pragma unroll
                for (int i4 = 0; i4 < 4; i4++) {
                    int cl = cg * 16 + i4 * 4;
                    int cglob = kc * 32 + cl;
                    float4 A  = *(const float4*)(xb + b0 + cglob);
                    float4 Bv = *(const float4*)(xb + b1 + cglob);
                    float4 Cv = *(const float4*)(xb + b2 + cglob);
                    float4 Dv = *(const float4*)(xb + b3 + cglob);
                    float v0 = g0 * A.x + g1 * Bv.x + g2 * Cv.x + g3 * Dv.x;
                    float v1 = g0 * A.y + g1 * Bv.y + g2 * Cv.y + g3 * Dv.y;
                    float v2 = g0 * A.z + g1 * Bv.z + g2 * Cv.z + g3 * Dv.z;
                    float v3 = g0 * A.w + g1 * Bv.w + g2 * Cv.w + g3 * Dv.w;
                    uint2 pk = make_uint2(pack_bf2(v0, v1), pack_bf2(v2, v3));
                    *(uint2*)(Vl + ((cl >> 3) * 128 + pos_g) * 8 + (cl & 7)) = pk;
                }
            }
            __syncthreads();
            // one K=32 MFMA step: 16 MFMAs per wave
            {
                const bf16x8* Af = (const bf16x8*)Al;
                const bf16x8* Bf = (const bf16x8*)Vl;
                bf16x8 av[4], bv[4];
#pragma unroll
                for (int i = 0; i < 4; i++) av[i] = Af[q * 128 + m0 + i * 16 + l15];
#pragma unroll
                for (int j = 0; j < 4; j++) bv[j] = Bf[q * 128 + n0 + j * 16 + l15];
#pragma unroll
                for (int i = 0; i < 4; i++)
#pragma unroll
                    for (int j = 0; j < 4; j++)
                        acc[i][j] = __builtin_amdgcn_mfma_f32_16x16x32_bf16(av[i], bv[j], acc[i][j], 0, 0, 0);
            }
        }
    }

    // epilogue: write out + BN partial sums
    __syncthreads();
    if (t < 128) { red[0][t] = 0.f; red[1][t] = 0.f; }
    __syncthreads();
    float* outb = out + ((size_t)(b * O_ + o0)) * HW_ + h * W_;
#pragma unroll
    for (int i = 0; i < 4; i++) {
#pragma unroll
        for (int r = 0; r < 4; r++) {
            int o_loc = m0 + i * 16 + q * 4 + r;
            float s = 0.f, s2 = 0.f;
#pragma unroll
            for (int j = 0; j < 4; j++) {
                float v = acc[i][j][r];
                s += v; s2 += v * v;
                outb[(size_t)o_loc * HW_ + n0 + j * 16 + l15] = v;
            }
            s  += __shfl_xor(s, 1);  s  += __shfl_xor(s, 2);  s  += __shfl_xor(s, 4);  s  += __shfl_xor(s, 8);
            s2 += __shfl_xor(s2, 1); s2 += __shfl_xor(s2, 2); s2 += __shfl_xor(s2, 4); s2 += __shfl_xor(s2, 8);
            if (l15 == 0) {
                atomicAdd(&red[0][o_loc], s);
                atomicAdd(&red[1][o_loc], s2);
            }
        }
    }
    __syncthreads();
    if (t < 128) {
        atomicAdd(&stats[o0 + t], red[0][t]);
        atomicAdd(&stats[256 + o0 + t], red[1][t]);
    }
}

// ---------------- K4: BN stats finalize ----------------
__global__ void k_bnstats(float* __restrict__ stats,
                          const float* __restrict__ gamma,
                          const float* __restrict__ beta) {
    int t = threadIdx.x;  // 256
    float s = stats[t], s2 = stats[256 + t];
    float mean = s * (1.f / 65536.f);
    float var = s2 * (1.f / 65536.f) - mean * mean;
    float sc = gamma[t] * rsqrtf(var + 1e-5f);
    float sh = beta[t] - mean * sc;
    stats[512 + t] = sc;
    stats[768 + t] = sh;
}

// ---------------- K5: normalize + leaky ReLU (in-place on d_out) ----------------
__global__ __launch_bounds__(256) void k_apply(float* __restrict__ out,
                                               const float* __restrict__ stats) {
    int idx = blockIdx.x * 256 + threadIdx.x;  // float4 index
    int e = idx * 4;
    int o = (e >> 14) & 255;
    float sc = stats[512 + o], sh = stats[768 + o];
    float4 v = *(float4*)(out + e);
    v.x = v.x * sc + sh; v.x = (v.x >= 0.f) ? v.x : 0.1f * v.x;
    v.y = v.y * sc + sh; v.y = (v.y >= 0.f) ? v.y : 0.1f * v.y;
    v.z = v.z * sc + sh; v.z = (v.z >= 0.f) ? v.z : 0.1f * v.z;
    v.w = v.w * sc + sh; v.w = (v.w >= 0.f) ? v.w : 0.1f * v.w;
    *(float4*)(out + e) = v;
}

extern "C" void kernel_launch(void* const* d_in, const int* in_sizes, int n_in,
                              void* d_out, int out_size, void* d_ws, size_t ws_size,
                              hipStream_t stream) {
    const float* x      = (const float*)d_in[0];
    const float* p_w    = (const float*)d_in[1];
    const float* p_b    = (const float*)d_in[2];
    const float* w_conv = (const float*)d_in[3];
    const float* gamma  = (const float*)d_in[4];
    const float* beta   = (const float*)d_in[5];
    float* out = (float*)d_out;

    float* ws    = (float*)d_ws;
    float* xpad  = ws;
    float* off   = ws + OFF_OFF;
    unsigned short* wrepb = (unsigned short*)(ws + WREPB_OFF);
    float* stats = ws + STATS_OFF;

    hipMemsetAsync(xpad, 0, (size_t)XPAD_SZ * 4, stream);
    hipMemsetAsync(stats, 0, (size_t)STATS_SZ * 4, stream);

    k_transpose<<<dim3(W_ / 32, C_ / 32, B_ * H_), dim3(32, 8), 0, stream>>>(x, xpad);
    k_offconv<<<dim3(HW_ / 256, B_), 256, 0, stream>>>(xpad, p_w, p_b, off);
    k_repack<<<dim3((9 * C_ * O_ + 255) / 256), 256, 0, stream>>>(w_conv, wrepb);
    k_main<<<dim3(H_, 2, B_), 256, 0, stream>>>(xpad, off, wrepb, out, stats);
    k_bnstats<<<1, 256, 0, stream>>>(stats, gamma, beta);
    k_apply<<<dim3(16384), 256, 0, stream>>>(out, stats);
}

// Round 4
// 505.308 us; speedup vs baseline: 1.5713x; 1.1983x over previous
//
#include <hip/hip_runtime.h>
#include <cstdint>

typedef __attribute__((ext_vector_type(8))) short bf16x8;
typedef __attribute__((ext_vector_type(4))) float f32x4;

#define B_   4
#define C_   128
#define H_   128
#define W_   128
#define HP_  130
#define WP_  130
#define O_   256
#define HW_  (H_*W_)          // 16384

// ws layout (byte offsets)
#define XPAD_BYTES   (B_*HP_*WP_*C_*2)          // bf16 xpad: 17,305,600
#define OFF_BYTE     XPAD_BYTES
#define OFF_BYTES    (B_*HW_*18*4)              // 4,718,592
#define WREPB_BYTE   (OFF_BYTE + OFF_BYTES)
#define WREPB_BYTES  (9*C_*O_*2)                // 589,824
#define STATS_BYTE   (WREPB_BYTE + WREPB_BYTES)

__device__ __forceinline__ unsigned pack_bf2(float a, float b) {
    // (bf16(b) << 16) | bf16(a), round-half-up
    unsigned ua = __builtin_bit_cast(unsigned, a) + 0x8000u;
    unsigned ub = __builtin_bit_cast(unsigned, b) + 0x8000u;
    return __builtin_amdgcn_perm(ub, ua, 0x07060302u);
}

// ---------------- K1: NCHW fp32 -> padded NHWC bf16 transpose ----------------
__global__ void k_transpose(const float* __restrict__ x, unsigned short* __restrict__ xpad) {
    __shared__ float tile[32][33];   // [c_loc][w_loc]
    int w0 = blockIdx.x * 32, c0 = blockIdx.y * 32;
    int bh = blockIdx.z;
    int b = bh >> 7, h = bh & 127;
    int tx = threadIdx.x, ty = threadIdx.y;
#pragma unroll
    for (int i = 0; i < 4; i++) {
        int c = c0 + ty + i * 8;
        tile[ty + i * 8][tx] = x[((b * C_ + c) * H_ + h) * W_ + w0 + tx];
    }
    __syncthreads();
    int tid = ty * 32 + tx;
    int cp = tid & 15;      // channel pair 0..15 -> channels 2cp, 2cp+1
    int wl = tid >> 4;      // 0..15
#pragma unroll
    for (int i = 0; i < 2; i++) {
        int wll = wl + i * 16;
        int w = w0 + wll;
        unsigned v = pack_bf2(tile[2 * cp][wll], tile[2 * cp + 1][wll]);
        *(unsigned*)(&xpad[((size_t)((b * HP_ + h + 1) * WP_ + (w + 1))) * C_ + c0 + 2 * cp]) = v;
    }
}

// ---------------- K2: offset conv, reads NCHW x directly, writes off[b][j][pos] ----------------
__global__ __launch_bounds__(256) void k_offconv(const float* __restrict__ x,
                                                 const float* __restrict__ p_w,
                                                 const float* __restrict__ p_b,
                                                 float* __restrict__ offT) {
    int t = threadIdx.x;
    int b = blockIdx.y;
    int p = blockIdx.x * 256 + t;
    int h = p >> 7, w = p & 127;
    float acc[18];
#pragma unroll
    for (int j = 0; j < 18; j++) acc[j] = p_b[j];

    int hh[3], ww[3];
    bool hok[3], wok[3];
#pragma unroll
    for (int k = 0; k < 3; k++) {
        hh[k] = h + k - 1; hok[k] = (unsigned)hh[k] < 128u;
        ww[k] = w + k - 1; wok[k] = (unsigned)ww[k] < 128u;
    }

    for (int c = 0; c < C_; c++) {
        const float* xc = x + (((size_t)(b * C_ + c)) << 14);
        float xv[9];
#pragma unroll
        for (int kh = 0; kh < 3; kh++)
#pragma unroll
            for (int kw = 0; kw < 3; kw++) {
                bool ok = hok[kh] && wok[kw];
                int idx = ok ? (hh[kh] * W_ + ww[kw]) : 0;
                float v = xc[idx];
                xv[kh * 3 + kw] = ok ? v : 0.f;
            }
        const float* wc = p_w + c * 9;
#pragma unroll
        for (int j = 0; j < 18; j++) {
            const float* wj = wc + (size_t)j * C_ * 9;   // uniform address -> scalar loads
            float a = acc[j];
#pragma unroll
            for (int tp = 0; tp < 9; tp++) a += wj[tp] * xv[tp];
            acc[j] = a;
        }
    }
#pragma unroll
    for (int j = 0; j < 18; j++)
        offT[((size_t)(b * 18 + j)) * HW_ + p] = acc[j];
}

// ---------------- K2b: repack w_conv -> bf16 [n][kc2][ob][kq8][o128][ki8] ----------------
__global__ void k_repack(const float* __restrict__ w_conv, unsigned short* __restrict__ wrepb) {
    int i = blockIdx.x * 256 + threadIdx.x;
    if (i < 9 * C_ * O_) {
        int ki8   = i & 7;
        int o_loc = (i >> 3) & 127;
        int kq    = (i >> 10) & 7;
        int ob    = (i >> 13) & 1;
        int kc2   = (i >> 14) & 1;
        int n     = i >> 15;
        int o = ob * 128 + o_loc;
        int c = kc2 * 64 + kq * 8 + ki8;
        float f = w_conv[(o * C_ + c) * 9 + n];
        unsigned u = __builtin_bit_cast(unsigned, f);
        u += 0x7fffu + ((u >> 16) & 1u);   // RNE
        wrepb[i] = (unsigned short)(u >> 16);
    }
}

// ---------------- K3: fused gather + bf16 MFMA GEMM + BN partial sums ----------------
__global__ __launch_bounds__(256, 4) void k_main(const unsigned short* __restrict__ xpad,
                                                 const float* __restrict__ offT,
                                                 const unsigned short* __restrict__ wrepb,
                                                 float* __restrict__ out,
                                                 float* __restrict__ stats) {
    __shared__ short Wl[8192];      // [kq8][o128][8]              16 KB
    __shared__ short Vl[8256];      // skewed: granule kq*129+pos  16.1 KB
    __shared__ int   pbase[4][128];
    __shared__ float pg[4][128];
    __shared__ float red[2][128];

    int t = threadIdx.x;
    int h  = blockIdx.x;
    int ob = blockIdx.y;
    int b  = blockIdx.z;
    int o0 = ob * 128;
    const unsigned short* xb = xpad + (size_t)b * HP_ * WP_ * C_;

    int lane = t & 63, wv = t >> 6;
    int q = lane >> 4, l15 = lane & 15;
    int m0 = (wv & 1) * 64, n0 = (wv >> 1) * 64;
    int c8g = t & 7, posb = t >> 3;   // gather mapping: channels innermost

    f32x4 acc[4][4];
#pragma unroll
    for (int i = 0; i < 4; i++)
#pragma unroll
        for (int j = 0; j < 4; j++) acc[i][j] = (f32x4){0.f, 0.f, 0.f, 0.f};

    for (int n = 0; n < 9; n++) {
        __syncthreads();
        if (t < 128) {
            int w = t;
            float offx = offT[((size_t)(b * 18 + n)) * HW_ + h * W_ + w];
            float offy = offT[((size_t)(b * 18 + 9 + n)) * HW_ + h * W_ + w];
            int dxn = n / 3 - 1, dyn = n % 3 - 1;
            float px = (float)(h + 1 + dxn) + offx;
            float py = (float)(w + 1 + dyn) + offy;
            float pcx = fminf(fmaxf(px, 0.f), 129.f);
            float pcy = fminf(fmaxf(py, 0.f), 129.f);
            float fx = floorf(px), fy = floorf(py);
            float q0x = fminf(fmaxf(fx, 0.f), 129.f);
            float q0y = fminf(fmaxf(fy, 0.f), 129.f);
            float q1x = fminf(fmaxf(fx + 1.f, 0.f), 129.f);
            float q1y = fminf(fmaxf(fy + 1.f, 0.f), 129.f);
            float wx0 = 1.f + (q0x - pcx), wx1 = 1.f - (q1x - pcx);
            float wy0 = 1.f + (q0y - pcy), wy1 = 1.f - (q1y - pcy);
            int i0x = (int)q0x, i0y = (int)q0y, i1x = (int)q1x, i1y = (int)q1y;
            pbase[0][w] = (i0x * WP_ + i0y) * C_;
            pbase[1][w] = (i1x * WP_ + i1y) * C_;
            pbase[2][w] = (i0x * WP_ + i1y) * C_;
            pbase[3][w] = (i1x * WP_ + i0y) * C_;
            pg[0][w] = wx0 * wy0;
            pg[1][w] = wx1 * wy1;
            pg[2][w] = wx0 * wy1;
            pg[3][w] = wx1 * wy0;
        }
        for (int kc2 = 0; kc2 < 2; kc2++) {
            __syncthreads();
            // stage W chunk: 1024 granules of 16B, contiguous
            {
                const uint4* wsrc = (const uint4*)(wrepb + ((size_t)((n * 2 + kc2) * 2 + ob)) * 8192);
                uint4* wd = (uint4*)Wl;
#pragma unroll
                for (int r = 0; r < 4; r++) wd[r * 256 + t] = wsrc[r * 256 + t];
            }
            // gather V chunk: 64 ch x 128 pos, channel-contiguous lanes
            {
                int cof = kc2 * 64 + c8g * 8;
#pragma unroll
                for (int it = 0; it < 4; it++) {
                    int pos = posb + it * 32;
                    int b0 = pbase[0][pos], b1 = pbase[1][pos], b2 = pbase[2][pos], b3 = pbase[3][pos];
                    float g0 = pg[0][pos], g1 = pg[1][pos], g2 = pg[2][pos], g3 = pg[3][pos];
                    uint4 A  = *(const uint4*)(xb + b0 + cof);
                    uint4 Bv = *(const uint4*)(xb + b1 + cof);
                    uint4 Cv = *(const uint4*)(xb + b2 + cof);
                    uint4 Dv = *(const uint4*)(xb + b3 + cof);
                    unsigned outw[4];
#pragma unroll
                    for (int k = 0; k < 4; k++) {
                        unsigned ua = (&A.x)[k], ub = (&Bv.x)[k], uc = (&Cv.x)[k], ud = (&Dv.x)[k];
                        float alo = __builtin_bit_cast(float, ua << 16), ahi = __builtin_bit_cast(float, ua & 0xffff0000u);
                        float blo = __builtin_bit_cast(float, ub << 16), bhi = __builtin_bit_cast(float, ub & 0xffff0000u);
                        float clo = __builtin_bit_cast(float, uc << 16), chi = __builtin_bit_cast(float, uc & 0xffff0000u);
                        float dlo = __builtin_bit_cast(float, ud << 16), dhi = __builtin_bit_cast(float, ud & 0xffff0000u);
                        float vlo = g0 * alo + g1 * blo + g2 * clo + g3 * dlo;
                        float vhi = g0 * ahi + g1 * bhi + g2 * chi + g3 * dhi;
                        outw[k] = pack_bf2(vlo, vhi);
                    }
                    *(uint4*)&Vl[(size_t)(c8g * 129 + pos) * 8] = make_uint4(outw[0], outw[1], outw[2], outw[3]);
                }
            }
            __syncthreads();
            // MFMA: K=64 chunk = 2 K-steps of 32
            {
                const bf16x8* Af = (const bf16x8*)Wl;
                const bf16x8* Bf = (const bf16x8*)Vl;
#pragma unroll
                for (int ks = 0; ks < 2; ks++) {
                    int kq = ks * 4 + q;
                    bf16x8 av[4], bv[4];
#pragma unroll
                    for (int i = 0; i < 4; i++) av[i] = Af[kq * 128 + m0 + i * 16 + l15];
#pragma unroll
                    for (int j = 0; j < 4; j++) bv[j] = Bf[kq * 129 + n0 + j * 16 + l15];
#pragma unroll
                    for (int i = 0; i < 4; i++)
#pragma unroll
                        for (int j = 0; j < 4; j++)
                            acc[i][j] = __builtin_amdgcn_mfma_f32_16x16x32_bf16(av[i], bv[j], acc[i][j], 0, 0, 0);
                }
            }
        }
    }

    // epilogue: write out + BN partial sums
    __syncthreads();
    if (t < 128) { red[0][t] = 0.f; red[1][t] = 0.f; }
    __syncthreads();
    float* outb = out + ((size_t)(b * O_ + o0)) * HW_ + h * W_;
#pragma unroll
    for (int i = 0; i < 4; i++) {
#pragma unroll
        for (int r = 0; r < 4; r++) {
            int o_loc = m0 + i * 16 + q * 4 + r;
            float s = 0.f, s2 = 0.f;
#pragma unroll
            for (int j = 0; j < 4; j++) {
                float v = acc[i][j][r];
                s += v; s2 += v * v;
                outb[(size_t)o_loc * HW_ + n0 + j * 16 + l15] = v;
            }
            s  += __shfl_xor(s, 1);  s  += __shfl_xor(s, 2);  s  += __shfl_xor(s, 4);  s  += __shfl_xor(s, 8);
            s2 += __shfl_xor(s2, 1); s2 += __shfl_xor(s2, 2); s2 += __shfl_xor(s2, 4); s2 += __shfl_xor(s2, 8);
            if (l15 == 0) {
                atomicAdd(&red[0][o_loc], s);
                atomicAdd(&red[1][o_loc], s2);
            }
        }
    }
    __syncthreads();
    if (t < 128) {
        atomicAdd(&stats[o0 + t], red[0][t]);
        atomicAdd(&stats[256 + o0 + t], red[1][t]);
    }
}

// ---------------- K4: BN stats finalize ----------------
__global__ void k_bnstats(float* __restrict__ stats,
                          const float* __restrict__ gamma,
                          const float* __restrict__ beta) {
    int t = threadIdx.x;  // 256
    float s = stats[t], s2 = stats[256 + t];
    float mean = s * (1.f / 65536.f);
    float var = s2 * (1.f / 65536.f) - mean * mean;
    float sc = gamma[t] * rsqrtf(var + 1e-5f);
    float sh = beta[t] - mean * sc;
    stats[512 + t] = sc;
    stats[768 + t] = sh;
}

// ---------------- K5: normalize + leaky ReLU (in-place on d_out) ----------------
__global__ __launch_bounds__(256) void k_apply(float* __restrict__ out,
                                               const float* __restrict__ stats) {
    int idx = blockIdx.x * 256 + threadIdx.x;
    int e = idx * 4;
    int o = (e >> 14) & 255;
    float sc = stats[512 + o], sh = stats[768 + o];
    float4 v = *(float4*)(out + e);
    v.x = v.x * sc + sh; v.x = (v.x >= 0.f) ? v.x : 0.1f * v.x;
    v.y = v.y * sc + sh; v.y = (v.y >= 0.f) ? v.y : 0.1f * v.y;
    v.z = v.z * sc + sh; v.z = (v.z >= 0.f) ? v.z : 0.1f * v.z;
    v.w = v.w * sc + sh; v.w = (v.w >= 0.f) ? v.w : 0.1f * v.w;
    *(float4*)(out + e) = v;
}

extern "C" void kernel_launch(void* const* d_in, const int* in_sizes, int n_in,
                              void* d_out, int out_size, void* d_ws, size_t ws_size,
                              hipStream_t stream) {
    const float* x      = (const float*)d_in[0];
    const float* p_w    = (const float*)d_in[1];
    const float* p_b    = (const float*)d_in[2];
    const float* w_conv = (const float*)d_in[3];
    const float* gamma  = (const float*)d_in[4];
    const float* beta   = (const float*)d_in[5];
    float* out = (float*)d_out;

    char* wsb = (char*)d_ws;
    unsigned short* xpad  = (unsigned short*)wsb;
    float*          offT  = (float*)(wsb + OFF_BYTE);
    unsigned short* wrepb = (unsigned short*)(wsb + WREPB_BYTE);
    float*          stats = (float*)(wsb + STATS_BYTE);

    hipMemsetAsync(xpad, 0, (size_t)XPAD_BYTES, stream);
    hipMemsetAsync(stats, 0, 4096, stream);

    k_transpose<<<dim3(W_ / 32, C_ / 32, B_ * H_), dim3(32, 8), 0, stream>>>(x, xpad);
    k_offconv<<<dim3(HW_ / 256, B_), 256, 0, stream>>>(x, p_w, p_b, offT);
    k_repack<<<dim3((9 * C_ * O_ + 255) / 256), 256, 0, stream>>>(w_conv, wrepb);
    k_main<<<dim3(H_, 2, B_), 256, 0, stream>>>(xpad, offT, wrepb, out, stats);
    k_bnstats<<<1, 256, 0, stream>>>(stats, gamma, beta);
    k_apply<<<dim3(16384), 256, 0, stream>>>(out, stats);
}

// Round 5
// 364.460 us; speedup vs baseline: 2.1785x; 1.3865x over previous
//
#include <hip/hip_runtime.h>
#include <cstdint>

typedef __attribute__((ext_vector_type(8))) short bf16x8;
typedef __attribute__((ext_vector_type(4))) float f32x4;

#define B_   4
#define C_   128
#define H_   128
#define W_   128
#define HP_  130
#define WP_  130
#define O_   256
#define HW_  (H_*W_)          // 16384

// ws layout (byte offsets)
#define XPAD_BYTES   (B_*HP_*WP_*C_*2)          // bf16 xpad: 17,305,600
#define OFF_BYTE     XPAD_BYTES
#define OFF_BYTES    (B_*HW_*18*4)              // 4,718,592
#define WREPB_BYTE   (OFF_BYTE + OFF_BYTES)
#define WREPB_BYTES  (9*C_*O_*2)                // 589,824
#define STATS_BYTE   (WREPB_BYTE + WREPB_BYTES)

__device__ __forceinline__ unsigned pack_bf2(float a, float b) {
    // (bf16(b) << 16) | bf16(a), round-half-up
    unsigned ua = __builtin_bit_cast(unsigned, a) + 0x8000u;
    unsigned ub = __builtin_bit_cast(unsigned, b) + 0x8000u;
    return __builtin_amdgcn_perm(ub, ua, 0x07060302u);
}

// ---------------- K1: NCHW fp32 -> padded NHWC bf16 transpose ----------------
__global__ void k_transpose(const float* __restrict__ x, unsigned short* __restrict__ xpad) {
    __shared__ float tile[32][33];   // [c_loc][w_loc]
    int w0 = blockIdx.x * 32, c0 = blockIdx.y * 32;
    int bh = blockIdx.z;
    int b = bh >> 7, h = bh & 127;
    int tx = threadIdx.x, ty = threadIdx.y;
#pragma unroll
    for (int i = 0; i < 4; i++) {
        int c = c0 + ty + i * 8;
        tile[ty + i * 8][tx] = x[((b * C_ + c) * H_ + h) * W_ + w0 + tx];
    }
    __syncthreads();
    int tid = ty * 32 + tx;
    int cp = tid & 15;      // channel pair 0..15 -> channels 2cp, 2cp+1
    int wl = tid >> 4;      // 0..15
#pragma unroll
    for (int i = 0; i < 2; i++) {
        int wll = wl + i * 16;
        int w = w0 + wll;
        unsigned v = pack_bf2(tile[2 * cp][wll], tile[2 * cp + 1][wll]);
        *(unsigned*)(&xpad[((size_t)((b * HP_ + h + 1) * WP_ + (w + 1))) * C_ + c0 + 2 * cp]) = v;
    }
}

// ---------------- K2: offset conv, j-split (6 per block), writes off[b][j][pos] ----------------
__global__ __launch_bounds__(256) void k_offconv(const float* __restrict__ x,
                                                 const float* __restrict__ p_w,
                                                 const float* __restrict__ p_b,
                                                 float* __restrict__ offT) {
    int t = threadIdx.x;
    int jg = blockIdx.y;              // 0..2 -> j in [6jg, 6jg+6)
    int b = blockIdx.z;
    int p = blockIdx.x * 256 + t;
    int h = p >> 7, w = p & 127;
    float acc[6];
#pragma unroll
    for (int jl = 0; jl < 6; jl++) acc[jl] = p_b[jg * 6 + jl];

    int hh[3], ww[3];
    bool hok[3], wok[3];
#pragma unroll
    for (int k = 0; k < 3; k++) {
        hh[k] = h + k - 1; hok[k] = (unsigned)hh[k] < 128u;
        ww[k] = w + k - 1; wok[k] = (unsigned)ww[k] < 128u;
    }

    for (int c = 0; c < C_; c++) {
        const float* xc = x + (((size_t)(b * C_ + c)) << 14);
        float xv[9];
#pragma unroll
        for (int kh = 0; kh < 3; kh++)
#pragma unroll
            for (int kw = 0; kw < 3; kw++) {
                bool ok = hok[kh] && wok[kw];
                int idx = ok ? (hh[kh] * W_ + ww[kw]) : 0;
                float v = xc[idx];
                xv[kh * 3 + kw] = ok ? v : 0.f;
            }
#pragma unroll
        for (int jl = 0; jl < 6; jl++) {
            const float* wj = p_w + ((size_t)(jg * 6 + jl) * C_ + c) * 9;  // uniform -> scalar loads
            float a = acc[jl];
#pragma unroll
            for (int tp = 0; tp < 9; tp++) a += wj[tp] * xv[tp];
            acc[jl] = a;
        }
    }
#pragma unroll
    for (int jl = 0; jl < 6; jl++)
        offT[((size_t)(b * 18 + jg * 6 + jl)) * HW_ + p] = acc[jl];
}

// ---------------- K2b: repack w_conv -> bf16 [n][kc2][ob][kq8][o128][ki8] ----------------
__global__ void k_repack(const float* __restrict__ w_conv, unsigned short* __restrict__ wrepb) {
    int i = blockIdx.x * 256 + threadIdx.x;
    if (i < 9 * C_ * O_) {
        int ki8   = i & 7;
        int o_loc = (i >> 3) & 127;
        int kq    = (i >> 10) & 7;
        int ob    = (i >> 13) & 1;
        int kc2   = (i >> 14) & 1;
        int n     = i >> 15;
        int o = ob * 128 + o_loc;
        int c = kc2 * 64 + kq * 8 + ki8;
        float f = w_conv[(o * C_ + c) * 9 + n];
        unsigned u = __builtin_bit_cast(unsigned, f);
        u += 0x7fffu + ((u >> 16) & 1u);   // RNE
        wrepb[i] = (unsigned short)(u >> 16);
    }
}

// ---------------- K3: fused gather + bf16 MFMA GEMM + BN partial sums ----------------
__global__ __launch_bounds__(256, 4) void k_main(const unsigned short* __restrict__ xpad,
                                                 const float* __restrict__ offT,
                                                 const unsigned short* __restrict__ wrepb,
                                                 float* __restrict__ out,
                                                 float* __restrict__ stats) {
    __shared__ short Wl[8192];      // [kq8][o128][8]              16 KB
    __shared__ short Vl[8256];      // skewed: granule kq*129+pos  16.1 KB
    __shared__ int   pbase[4][128];
    __shared__ float pg[4][128];
    __shared__ float red[2][128];

    int t = threadIdx.x;
    int h  = blockIdx.x;
    int ob = blockIdx.y;
    int b  = blockIdx.z;
    int o0 = ob * 128;
    const unsigned short* xb = xpad + (size_t)b * HP_ * WP_ * C_;

    int lane = t & 63, wv = t >> 6;
    int q = lane >> 4, l15 = lane & 15;
    int m0 = (wv & 1) * 64, n0 = (wv >> 1) * 64;
    int c8g = t & 7, posb = t >> 3;   // gather mapping: channels innermost

    f32x4 acc[4][4];
#pragma unroll
    for (int i = 0; i < 4; i++)
#pragma unroll
        for (int j = 0; j < 4; j++) acc[i][j] = (f32x4){0.f, 0.f, 0.f, 0.f};

    for (int n = 0; n < 9; n++) {
        __syncthreads();
        if (t < 128) {
            int w = t;
            float offx = offT[((size_t)(b * 18 + n)) * HW_ + h * W_ + w];
            float offy = offT[((size_t)(b * 18 + 9 + n)) * HW_ + h * W_ + w];
            int dxn = n / 3 - 1, dyn = n % 3 - 1;
            float px = (float)(h + 1 + dxn) + offx;
            float py = (float)(w + 1 + dyn) + offy;
            float pcx = fminf(fmaxf(px, 0.f), 129.f);
            float pcy = fminf(fmaxf(py, 0.f), 129.f);
            float fx = floorf(px), fy = floorf(py);
            float q0x = fminf(fmaxf(fx, 0.f), 129.f);
            float q0y = fminf(fmaxf(fy, 0.f), 129.f);
            float q1x = fminf(fmaxf(fx + 1.f, 0.f), 129.f);
            float q1y = fminf(fmaxf(fy + 1.f, 0.f), 129.f);
            float wx0 = 1.f + (q0x - pcx), wx1 = 1.f - (q1x - pcx);
            float wy0 = 1.f + (q0y - pcy), wy1 = 1.f - (q1y - pcy);
            int i0x = (int)q0x, i0y = (int)q0y, i1x = (int)q1x, i1y = (int)q1y;
            pbase[0][w] = (i0x * WP_ + i0y) * C_;
            pbase[1][w] = (i1x * WP_ + i1y) * C_;
            pbase[2][w] = (i0x * WP_ + i1y) * C_;
            pbase[3][w] = (i1x * WP_ + i0y) * C_;
            pg[0][w] = wx0 * wy0;
            pg[1][w] = wx1 * wy1;
            pg[2][w] = wx0 * wy1;
            pg[3][w] = wx1 * wy0;
        }
        for (int kc2 = 0; kc2 < 2; kc2++) {
            __syncthreads();
            // stage W chunk: 1024 granules of 16B, contiguous
            {
                const uint4* wsrc = (const uint4*)(wrepb + ((size_t)((n * 2 + kc2) * 2 + ob)) * 8192);
                uint4* wd = (uint4*)Wl;
#pragma unroll
                for (int r = 0; r < 4; r++) wd[r * 256 + t] = wsrc[r * 256 + t];
            }
            // gather V chunk: 64 ch x 128 pos, channel-contiguous lanes
            {
                int cof = kc2 * 64 + c8g * 8;
#pragma unroll
                for (int it = 0; it < 4; it++) {
                    int pos = posb + it * 32;
                    int b0 = pbase[0][pos], b1 = pbase[1][pos], b2 = pbase[2][pos], b3 = pbase[3][pos];
                    float g0 = pg[0][pos], g1 = pg[1][pos], g2 = pg[2][pos], g3 = pg[3][pos];
                    uint4 A  = *(const uint4*)(xb + b0 + cof);
                    uint4 Bv = *(const uint4*)(xb + b1 + cof);
                    uint4 Cv = *(const uint4*)(xb + b2 + cof);
                    uint4 Dv = *(const uint4*)(xb + b3 + cof);
                    unsigned outw[4];
#pragma unroll
                    for (int k = 0; k < 4; k++) {
                        unsigned ua = (&A.x)[k], ub = (&Bv.x)[k], uc = (&Cv.x)[k], ud = (&Dv.x)[k];
                        float alo = __builtin_bit_cast(float, ua << 16), ahi = __builtin_bit_cast(float, ua & 0xffff0000u);
                        float blo = __builtin_bit_cast(float, ub << 16), bhi = __builtin_bit_cast(float, ub & 0xffff0000u);
                        float clo = __builtin_bit_cast(float, uc << 16), chi = __builtin_bit_cast(float, uc & 0xffff0000u);
                        float dlo = __builtin_bit_cast(float, ud << 16), dhi = __builtin_bit_cast(float, ud & 0xffff0000u);
                        float vlo = g0 * alo + g1 * blo + g2 * clo + g3 * dlo;
                        float vhi = g0 * ahi + g1 * bhi + g2 * chi + g3 * dhi;
                        outw[k] = pack_bf2(vlo, vhi);
                    }
                    *(uint4*)&Vl[(size_t)(c8g * 129 + pos) * 8] = make_uint4(outw[0], outw[1], outw[2], outw[3]);
                }
            }
            __syncthreads();
            // MFMA: K=64 chunk = 2 K-steps of 32
            {
                const bf16x8* Af = (const bf16x8*)Wl;
                const bf16x8* Bf = (const bf16x8*)Vl;
#pragma unroll
                for (int ks = 0; ks < 2; ks++) {
                    int kq = ks * 4 + q;
                    bf16x8 av[4], bv[4];
#pragma unroll
                    for (int i = 0; i < 4; i++) av[i] = Af[kq * 128 + m0 + i * 16 + l15];
#pragma unroll
                    for (int j = 0; j < 4; j++) bv[j] = Bf[kq * 129 + n0 + j * 16 + l15];
#pragma unroll
                    for (int i = 0; i < 4; i++)
#pragma unroll
                        for (int j = 0; j < 4; j++)
                            acc[i][j] = __builtin_amdgcn_mfma_f32_16x16x32_bf16(av[i], bv[j], acc[i][j], 0, 0, 0);
                }
            }
        }
    }

    // epilogue: write out + BN partial sums
    __syncthreads();
    if (t < 128) { red[0][t] = 0.f; red[1][t] = 0.f; }
    __syncthreads();
    float* outb = out + ((size_t)(b * O_ + o0)) * HW_ + h * W_;
#pragma unroll
    for (int i = 0; i < 4; i++) {
#pragma unroll
        for (int r = 0; r < 4; r++) {
            int o_loc = m0 + i * 16 + q * 4 + r;
            float s = 0.f, s2 = 0.f;
#pragma unroll
            for (int j = 0; j < 4; j++) {
                float v = acc[i][j][r];
                s += v; s2 += v * v;
                outb[(size_t)o_loc * HW_ + n0 + j * 16 + l15] = v;
            }
            s  += __shfl_xor(s, 1);  s  += __shfl_xor(s, 2);  s  += __shfl_xor(s, 4);  s  += __shfl_xor(s, 8);
            s2 += __shfl_xor(s2, 1); s2 += __shfl_xor(s2, 2); s2 += __shfl_xor(s2, 4); s2 += __shfl_xor(s2, 8);
            if (l15 == 0) {
                atomicAdd(&red[0][o_loc], s);
                atomicAdd(&red[1][o_loc], s2);
            }
        }
    }
    __syncthreads();
    if (t < 128) {
        atomicAdd(&stats[o0 + t], red[0][t]);
        atomicAdd(&stats[256 + o0 + t], red[1][t]);
    }
}

// ---------------- K4: BN stats finalize ----------------
__global__ void k_bnstats(float* __restrict__ stats,
                          const float* __restrict__ gamma,
                          const float* __restrict__ beta) {
    int t = threadIdx.x;  // 256
    float s = stats[t], s2 = stats[256 + t];
    float mean = s * (1.f / 65536.f);
    float var = s2 * (1.f / 65536.f) - mean * mean;
    float sc = gamma[t] * rsqrtf(var + 1e-5f);
    float sh = beta[t] - mean * sc;
    stats[512 + t] = sc;
    stats[768 + t] = sh;
}

// ---------------- K5: normalize + leaky ReLU (in-place on d_out) ----------------
__global__ __launch_bounds__(256) void k_apply(float* __restrict__ out,
                                               const float* __restrict__ stats) {
    int idx = blockIdx.x * 256 + threadIdx.x;
    int e = idx * 4;
    int o = (e >> 14) & 255;
    float sc = stats[512 + o], sh = stats[768 + o];
    float4 v = *(float4*)(out + e);
    v.x = v.x * sc + sh; v.x = (v.x >= 0.f) ? v.x : 0.1f * v.x;
    v.y = v.y * sc + sh; v.y = (v.y >= 0.f) ? v.y : 0.1f * v.y;
    v.z = v.z * sc + sh; v.z = (v.z >= 0.f) ? v.z : 0.1f * v.z;
    v.w = v.w * sc + sh; v.w = (v.w >= 0.f) ? v.w : 0.1f * v.w;
    *(float4*)(out + e) = v;
}

extern "C" void kernel_launch(void* const* d_in, const int* in_sizes, int n_in,
                              void* d_out, int out_size, void* d_ws, size_t ws_size,
                              hipStream_t stream) {
    const float* x      = (const float*)d_in[0];
    const float* p_w    = (const float*)d_in[1];
    const float* p_b    = (const float*)d_in[2];
    const float* w_conv = (const float*)d_in[3];
    const float* gamma  = (const float*)d_in[4];
    const float* beta   = (const float*)d_in[5];
    float* out = (float*)d_out;

    char* wsb = (char*)d_ws;
    unsigned short* xpad  = (unsigned short*)wsb;
    float*          offT  = (float*)(wsb + OFF_BYTE);
    unsigned short* wrepb = (unsigned short*)(wsb + WREPB_BYTE);
    float*          stats = (float*)(wsb + STATS_BYTE);

    hipMemsetAsync(xpad, 0, (size_t)XPAD_BYTES, stream);
    hipMemsetAsync(stats, 0, 4096, stream);

    k_transpose<<<dim3(W_ / 32, C_ / 32, B_ * H_), dim3(32, 8), 0, stream>>>(x, xpad);
    k_offconv<<<dim3(HW_ / 256, 3, B_), 256, 0, stream>>>(x, p_w, p_b, offT);
    k_repack<<<dim3((9 * C_ * O_ + 255) / 256), 256, 0, stream>>>(w_conv, wrepb);
    k_main<<<dim3(H_, 2, B_), 256, 0, stream>>>(xpad, offT, wrepb, out, stats);
    k_bnstats<<<1, 256, 0, stream>>>(stats, gamma, beta);
    k_apply<<<dim3(16384), 256, 0, stream>>>(out, stats);
}